// Round 13
// baseline (453.496 us; speedup 1.0000x reference)
//
#include <hip/hip_runtime.h>
#include <stdint.h>

#define NB 64
#define NR 1152
#define NI 64
#define NC 32
#define NO 32
#define NCC 8   // c-chunk: P chunk = 75.5 MB, L3-resident, reused per chunk

typedef float float4v __attribute__((ext_vector_type(4)));

// ---------------------------------------------------------------------------
// T0: transpose x[b,r,i] -> xT[r,i,b]  (one-time, 19 MB each way, ~6 us)
// ---------------------------------------------------------------------------
__global__ __launch_bounds__(256, 4)
void k_xpose(const float* __restrict__ x, float* __restrict__ xT) {
  __shared__ float ts[64][65];
  const int r = blockIdx.x;
  const int t = threadIdx.x;
  {
    const int b = t >> 2, i0 = (t & 3) * 16;
    const float4* src = reinterpret_cast<const float4*>(x + ((size_t)b * NR + r) * NI + i0);
#pragma unroll
    for (int k = 0; k < 4; ++k) {
      const float4 v = src[k];
      ts[b][i0 + 4 * k + 0] = v.x; ts[b][i0 + 4 * k + 1] = v.y;
      ts[b][i0 + 4 * k + 2] = v.z; ts[b][i0 + 4 * k + 3] = v.w;
    }
  }
  __syncthreads();
  {
    const int i = t >> 2, b0 = (t & 3) * 16;
    float* dst = xT + ((size_t)r * NI + i) * NB + b0;
#pragma unroll
    for (int k = 0; k < 4; ++k) {
      *reinterpret_cast<float4*>(dst + 4 * k) =
          make_float4(ts[b0 + 4 * k + 0][i], ts[b0 + 4 * k + 1][i],
                      ts[b0 + 4 * k + 2][i], ts[b0 + 4 * k + 3][i]);
    }
  }
}

// ---------------------------------------------------------------------------
// K1: priors[cl,b,r,o] = sum_i xT[r,i,b] * W[c0+cl,r,i,o], fp32.
// Round-12 proven structure (218us, no spill, VALUBusy 38%), two deltas:
//   launch_bounds (256,5): 5 blocks/CU x 32KB = 160KB LDS, 20 waves/CU
//   chunk-local P index (cl) for the reused 75.5MB L3-resident P buffer.
// Wave = 1 r, zero barriers, wave-private 8KB LDS slice.
// Lane: bh = lane>>3 (b = bh*8+a), og = lane&7 (o = og*4+q); acc[8][4]=32 VGPR.
// ---------------------------------------------------------------------------
__global__ __launch_bounds__(256, 5)
void k_priors(const float* __restrict__ xT, const float* __restrict__ W,
              float* __restrict__ P, int c0) {
  __shared__ __align__(16) float wlds[4][NI * NO];  // 4 x 8KB, wave-private

  const int tid  = threadIdx.x;
  const int lane = tid & 63;
  const int w    = tid >> 6;
  const int cl   = blockIdx.x;
  const int c    = c0 + cl;
  const int r    = blockIdx.y * 4 + w;
  const int og   = lane & 7;        // o = og*4 + 0..3
  const int bh   = lane >> 3;       // b = bh*8 + 0..7

  const float* Wr = W + ((size_t)c * NR + r) * (NI * NO);   // 2048 floats
  float* wb = &wlds[w][0];

  // stage whole 8KB W tile: 8 x (1KB-coalesced NT load -> LDS write)
#pragma unroll
  for (int k = 0; k < 8; ++k) {
    const float4v s = __builtin_nontemporal_load(
        reinterpret_cast<const float4v*>(Wr + k * 256 + lane * 4));
    *reinterpret_cast<float4v*>(wb + k * 256 + lane * 4) = s;
  }

  float acc[8][4];
#pragma unroll
  for (int a = 0; a < 8; ++a)
#pragma unroll
    for (int q = 0; q < 4; ++q) acc[a][q] = 0.f;

  const float* xrow = xT + (size_t)r * (NI * NB) + bh * 8;

#pragma unroll 8
  for (int i = 0; i < NI; ++i) {
    const float4 xa = *reinterpret_cast<const float4*>(xrow + i * NB);
    const float4 xb = *reinterpret_cast<const float4*>(xrow + i * NB + 4);
    const float4 wv = *reinterpret_cast<const float4*>(wb + i * NO + og * 4);
    const float xv[8] = {xa.x, xa.y, xa.z, xa.w, xb.x, xb.y, xb.z, xb.w};
    const float wq[4] = {wv.x, wv.y, wv.z, wv.w};
#pragma unroll
    for (int a = 0; a < 8; ++a)
#pragma unroll
      for (int q = 0; q < 4; ++q)
        acc[a][q] = fmaf(xv[a], wq[q], acc[a][q]);
  }

#pragma unroll
  for (int a = 0; a < 8; ++a) {
    const int b = bh * 8 + a;
    float* dst = P + (((size_t)cl * NB + b) * NR + r) * NO + og * 4;
    *reinterpret_cast<float4*>(dst) =
        make_float4(acc[a][0], acc[a][1], acc[a][2], acc[a][3]);
  }
}

// ---------------------------------------------------------------------------
// K2: full 3-iteration routing for one (c,b). block 1024 (16 waves).
// P slice read from the L3-resident chunk buffer exactly once.
// ---------------------------------------------------------------------------
__device__ __forceinline__ void merge4(float& m, float& Z, float4& T,
                                       float m2, float Z2, const float4& T2) {
  const float mn = fmaxf(m, m2);
  const float a1 = __expf(m - mn), a2 = __expf(m2 - mn);
  Z   = Z * a1 + Z2 * a2;
  T.x = T.x * a1 + T2.x * a2;
  T.y = T.y * a1 + T2.y * a2;
  T.z = T.z * a1 + T2.z * a2;
  T.w = T.w * a1 + T2.w * a2;
  m = mn;
}

__global__ __launch_bounds__(1024, 1)
void k_route(const float* __restrict__ P, float* __restrict__ out, int c0) {
  __shared__ float red_s[16][8][8];  // [wave][slice][m,Z,T0..3,pad2]
  __shared__ float u_s[NO];

  const int tid  = threadIdx.x;
  const int lane = tid & 63;
  const int wave = tid >> 6;
  const int sl   = tid & 7;   // o-slice: o = sl*4 + 0..3
  const int grp  = tid >> 3;  // row group 0..127; rows r = grp + 128*j
  const int b    = blockIdx.x;
  const int cl   = blockIdx.y;
  const int c    = c0 + cl;
  const float* Pb = P + ((size_t)cl * NB + b) * ((size_t)NR * NO);

  float4 p[9];
#pragma unroll
  for (int j = 0; j < 9; ++j)
    p[j] = *reinterpret_cast<const float4*>(Pb + (size_t)(grp + 128 * j) * NO + sl * 4);

  // ---- iteration 0: uniform softmax -> S0 = mean_r p ----
  {
    float4 T = p[0];
#pragma unroll
    for (int j = 1; j < 9; ++j) {
      T.x += p[j].x; T.y += p[j].y; T.z += p[j].z; T.w += p[j].w;
    }
#pragma unroll
    for (int off = 8; off <= 32; off <<= 1) {
      T.x += __shfl_xor(T.x, off); T.y += __shfl_xor(T.y, off);
      T.z += __shfl_xor(T.z, off); T.w += __shfl_xor(T.w, off);
    }
    if (lane < 8) {
      red_s[wave][sl][2] = T.x; red_s[wave][sl][3] = T.y;
      red_s[wave][sl][4] = T.z; red_s[wave][sl][5] = T.w;
    }
  }
  __syncthreads();
  if (tid < 8) {
    float4 S = make_float4(0.f, 0.f, 0.f, 0.f);
#pragma unroll
    for (int ww = 0; ww < 16; ++ww) {
      S.x += red_s[ww][tid][2]; S.y += red_s[ww][tid][3];
      S.z += red_s[ww][tid][4]; S.w += red_s[ww][tid][5];
    }
    S.x *= (1.f / NR); S.y *= (1.f / NR); S.z *= (1.f / NR); S.w *= (1.f / NR);
    float n2 = S.x * S.x + S.y * S.y + S.z * S.z + S.w * S.w;
    n2 += __shfl_xor(n2, 1); n2 += __shfl_xor(n2, 2); n2 += __shfl_xor(n2, 4);
    const float scale = n2 / ((1.f + n2) * sqrtf(n2));
    u_s[tid * 4 + 0] = S.x * scale; u_s[tid * 4 + 1] = S.y * scale;
    u_s[tid * 4 + 2] = S.z * scale; u_s[tid * 4 + 3] = S.w * scale;
  }
  __syncthreads();

  float4 u = *reinterpret_cast<const float4*>(&u_s[sl * 4]);
  float l1[9];

  for (int it = 1; it <= 2; ++it) {
    float m = -3.0e38f, Z = 0.f;
    float4 T = make_float4(0.f, 0.f, 0.f, 0.f);
#pragma unroll
    for (int j = 0; j < 9; ++j) {
      float d = p[j].x * u.x + p[j].y * u.y + p[j].z * u.z + p[j].w * u.w;
      d += __shfl_xor(d, 1); d += __shfl_xor(d, 2); d += __shfl_xor(d, 4);
      float l;
      if (it == 1) { l1[j] = d; l = d; }
      else         { l = l1[j] + d; }
      const float mn = fmaxf(m, l);
      const float a = __expf(m - mn);
      const float e = __expf(l - mn);
      Z   = Z * a + e;
      T.x = T.x * a + e * p[j].x; T.y = T.y * a + e * p[j].y;
      T.z = T.z * a + e * p[j].z; T.w = T.w * a + e * p[j].w;
      m = mn;
    }
#pragma unroll
    for (int off = 8; off <= 32; off <<= 1) {
      const float m2 = __shfl_xor(m, off);
      const float Z2 = __shfl_xor(Z, off);
      float4 T2;
      T2.x = __shfl_xor(T.x, off); T2.y = __shfl_xor(T.y, off);
      T2.z = __shfl_xor(T.z, off); T2.w = __shfl_xor(T.w, off);
      merge4(m, Z, T, m2, Z2, T2);
    }
    if (lane < 8) {
      red_s[wave][sl][0] = m;   red_s[wave][sl][1] = Z;
      red_s[wave][sl][2] = T.x; red_s[wave][sl][3] = T.y;
      red_s[wave][sl][4] = T.z; red_s[wave][sl][5] = T.w;
    }
    __syncthreads();
    if (tid < 8) {
      float mm = red_s[0][tid][0], ZZ = red_s[0][tid][1];
      float4 TT = make_float4(red_s[0][tid][2], red_s[0][tid][3],
                              red_s[0][tid][4], red_s[0][tid][5]);
#pragma unroll
      for (int ww = 1; ww < 16; ++ww) {
        const float4 T2 = make_float4(red_s[ww][tid][2], red_s[ww][tid][3],
                                      red_s[ww][tid][4], red_s[ww][tid][5]);
        merge4(mm, ZZ, TT, red_s[ww][tid][0], red_s[ww][tid][1], T2);
      }
      const float inv = 1.f / ZZ;
      float4 S = make_float4(TT.x * inv, TT.y * inv, TT.z * inv, TT.w * inv);
      float n2 = S.x * S.x + S.y * S.y + S.z * S.z + S.w * S.w;
      n2 += __shfl_xor(n2, 1); n2 += __shfl_xor(n2, 2); n2 += __shfl_xor(n2, 4);
      const float scale = n2 / ((1.f + n2) * sqrtf(n2));
      if (it == 1) {
        u_s[tid * 4 + 0] = S.x * scale; u_s[tid * 4 + 1] = S.y * scale;
        u_s[tid * 4 + 2] = S.z * scale; u_s[tid * 4 + 3] = S.w * scale;
      } else {
        *reinterpret_cast<float4*>(out + ((size_t)b * NC + c) * NO + tid * 4) =
            make_float4(S.x * scale, S.y * scale, S.z * scale, S.w * scale);
      }
    }
    __syncthreads();
    if (it == 1) u = *reinterpret_cast<const float4*>(&u_s[sl * 4]);
  }
}

extern "C" void kernel_launch(void* const* d_in, const int* in_sizes, int n_in,
                              void* d_out, int out_size, void* d_ws, size_t ws_size,
                              hipStream_t stream) {
  const float* x = (const float*)d_in[0];
  // d_in[1] (cond) is unused by the reference computation
  const float* W = (const float*)d_in[2];
  float* out = (float*)d_out;

  float* xT = (float*)d_ws;                       // 18.9 MB
  const size_t xT_floats = (size_t)NR * NI * NB;
  float* P = xT + xT_floats;                      // 75.5 MB, REUSED per chunk

  k_xpose<<<NR, 256, 0, stream>>>(x, xT);

  for (int c0 = 0; c0 < NC; c0 += NCC) {
    k_priors<<<dim3(NCC, NR / 4), 256, 0, stream>>>(xT, W, P, c0);
    k_route<<<dim3(NB, NCC), 1024, 0, stream>>>(P, out, c0);
  }
}

// Round 14
// 318.913 us; speedup vs baseline: 1.4220x; 1.4220x over previous
//
#include <hip/hip_runtime.h>
#include <stdint.h>

#define NB 64
#define NR 1152
#define NI 64
#define NC 32
#define NO 32

typedef float float4v __attribute__((ext_vector_type(4)));

// ---------------------------------------------------------------------------
// T0: transpose x[b,r,i] -> xT[r,i,b]  (one-time, 19 MB each way, ~6 us)
// ---------------------------------------------------------------------------
__global__ __launch_bounds__(256, 4)
void k_xpose(const float* __restrict__ x, float* __restrict__ xT) {
  __shared__ float ts[64][65];
  const int r = blockIdx.x;
  const int t = threadIdx.x;
  {
    const int b = t >> 2, i0 = (t & 3) * 16;
    const float4* src = reinterpret_cast<const float4*>(x + ((size_t)b * NR + r) * NI + i0);
#pragma unroll
    for (int k = 0; k < 4; ++k) {
      const float4 v = src[k];
      ts[b][i0 + 4 * k + 0] = v.x; ts[b][i0 + 4 * k + 1] = v.y;
      ts[b][i0 + 4 * k + 2] = v.z; ts[b][i0 + 4 * k + 3] = v.w;
    }
  }
  __syncthreads();
  {
    const int i = t >> 2, b0 = (t & 3) * 16;
    float* dst = xT + ((size_t)r * NI + i) * NB + b0;
#pragma unroll
    for (int k = 0; k < 4; ++k) {
      *reinterpret_cast<float4*>(dst + 4 * k) =
          make_float4(ts[b0 + 4 * k + 0][i], ts[b0 + 4 * k + 1][i],
                      ts[b0 + 4 * k + 2][i], ts[b0 + 4 * k + 3][i]);
    }
  }
}

// ---------------------------------------------------------------------------
// K1: priors[c,b,r,o] = sum_i xT[r,i,b] * W[c,r,i,o], fp32.
// Round-12 proven structure (218us, 52 VGPR, no spill) + ONE delta:
// explicit 2-iteration x-prefetch pipeline with NAMED registers (no arrays).
// Wave = 1 r, zero barriers, wave-private 8KB LDS W slice.
// Lane: bh = lane>>3 (b = bh*8+a), og = lane&7 (o = og*4+q); acc[8][4]=32 VGPR.
// Live set ~75 VGPR < 128 cap -> spill-proof.
// ---------------------------------------------------------------------------
__global__ __launch_bounds__(256, 4)
void k_priors(const float* __restrict__ xT, const float* __restrict__ W,
              float* __restrict__ P) {
  __shared__ __align__(16) float wlds[4][NI * NO];  // 4 x 8KB, wave-private

  const int tid  = threadIdx.x;
  const int lane = tid & 63;
  const int w    = tid >> 6;
  const int c    = blockIdx.x;
  const int r    = blockIdx.y * 4 + w;
  const int og   = lane & 7;        // o = og*4 + 0..3
  const int bh   = lane >> 3;       // b = bh*8 + 0..7

  const float* Wr = W + ((size_t)c * NR + r) * (NI * NO);   // 2048 floats
  float* wb = &wlds[w][0];

  // stage whole 8KB W tile: 8 x (1KB-coalesced NT load -> LDS write)
#pragma unroll
  for (int k = 0; k < 8; ++k) {
    const float4v s = __builtin_nontemporal_load(
        reinterpret_cast<const float4v*>(Wr + k * 256 + lane * 4));
    *reinterpret_cast<float4v*>(wb + k * 256 + lane * 4) = s;
  }

  float acc[8][4];
#pragma unroll
  for (int a = 0; a < 8; ++a)
#pragma unroll
    for (int q = 0; q < 4; ++q) acc[a][q] = 0.f;

  const float* xrow = xT + (size_t)r * (NI * NB) + bh * 8;

#define XLA(I) (*reinterpret_cast<const float4*>(xrow + (I) * NB))
#define XLB(I) (*reinterpret_cast<const float4*>(xrow + (I) * NB + 4))
#define FMA_STEP(I, XA, XB)                                                    \
  {                                                                            \
    const float4 wv = *reinterpret_cast<const float4*>(wb + (I) * NO + og * 4);\
    const float xv[8] = {XA.x, XA.y, XA.z, XA.w, XB.x, XB.y, XB.z, XB.w};     \
    const float wq[4] = {wv.x, wv.y, wv.z, wv.w};                              \
    _Pragma("unroll")                                                          \
    for (int a = 0; a < 8; ++a)                                                \
      _Pragma("unroll")                                                        \
      for (int q = 0; q < 4; ++q)                                              \
        acc[a][q] = fmaf(xv[a], wq[q], acc[a][q]);                             \
  }

  // software pipeline: prefetch x for i+2,i+3 while computing i,i+1
  float4 xa0 = XLA(0), xb0 = XLB(0);
  float4 xa1 = XLA(1), xb1 = XLB(1);

#pragma unroll 4
  for (int i = 0; i < NI - 2; i += 2) {
    const float4 na0 = XLA(i + 2), nb0 = XLB(i + 2);
    const float4 na1 = XLA(i + 3), nb1 = XLB(i + 3);
    FMA_STEP(i,     xa0, xb0)
    FMA_STEP(i + 1, xa1, xb1)
    xa0 = na0; xb0 = nb0; xa1 = na1; xb1 = nb1;
  }
  FMA_STEP(NI - 2, xa0, xb0)
  FMA_STEP(NI - 1, xa1, xb1)
#undef FMA_STEP
#undef XLA
#undef XLB

#pragma unroll
  for (int a = 0; a < 8; ++a) {
    const int b = bh * 8 + a;
    float* dst = P + (((size_t)c * NB + b) * NR + r) * NO + og * 4;
    *reinterpret_cast<float4*>(dst) =
        make_float4(acc[a][0], acc[a][1], acc[a][2], acc[a][3]);
  }
}

// ---------------------------------------------------------------------------
// K2: full 3-iteration routing for one (c,b). block 1024 (16 waves).
// 8 lanes per route-row (sl = o-slice of 4); P slice in registers p[9],
// read from global exactly once, coalesced 1 KB per wave instruction.
// ---------------------------------------------------------------------------
__device__ __forceinline__ void merge4(float& m, float& Z, float4& T,
                                       float m2, float Z2, const float4& T2) {
  const float mn = fmaxf(m, m2);
  const float a1 = __expf(m - mn), a2 = __expf(m2 - mn);
  Z   = Z * a1 + Z2 * a2;
  T.x = T.x * a1 + T2.x * a2;
  T.y = T.y * a1 + T2.y * a2;
  T.z = T.z * a1 + T2.z * a2;
  T.w = T.w * a1 + T2.w * a2;
  m = mn;
}

__global__ __launch_bounds__(1024, 1)
void k_route(const float* __restrict__ P, float* __restrict__ out) {
  __shared__ float red_s[16][8][8];  // [wave][slice][m,Z,T0..3,pad2]
  __shared__ float u_s[NO];

  const int tid  = threadIdx.x;
  const int lane = tid & 63;
  const int wave = tid >> 6;
  const int sl   = tid & 7;   // o-slice: o = sl*4 + 0..3
  const int grp  = tid >> 3;  // row group 0..127; rows r = grp + 128*j
  const int b    = blockIdx.x;
  const int c    = blockIdx.y;
  const float* Pb = P + ((size_t)c * NB + b) * ((size_t)NR * NO);

  float4 p[9];
#pragma unroll
  for (int j = 0; j < 9; ++j)
    p[j] = *reinterpret_cast<const float4*>(Pb + (size_t)(grp + 128 * j) * NO + sl * 4);

  // ---- iteration 0: uniform softmax -> S0 = mean_r p ----
  {
    float4 T = p[0];
#pragma unroll
    for (int j = 1; j < 9; ++j) {
      T.x += p[j].x; T.y += p[j].y; T.z += p[j].z; T.w += p[j].w;
    }
#pragma unroll
    for (int off = 8; off <= 32; off <<= 1) {
      T.x += __shfl_xor(T.x, off); T.y += __shfl_xor(T.y, off);
      T.z += __shfl_xor(T.z, off); T.w += __shfl_xor(T.w, off);
    }
    if (lane < 8) {
      red_s[wave][sl][2] = T.x; red_s[wave][sl][3] = T.y;
      red_s[wave][sl][4] = T.z; red_s[wave][sl][5] = T.w;
    }
  }
  __syncthreads();
  if (tid < 8) {
    float4 S = make_float4(0.f, 0.f, 0.f, 0.f);
#pragma unroll
    for (int ww = 0; ww < 16; ++ww) {
      S.x += red_s[ww][tid][2]; S.y += red_s[ww][tid][3];
      S.z += red_s[ww][tid][4]; S.w += red_s[ww][tid][5];
    }
    S.x *= (1.f / NR); S.y *= (1.f / NR); S.z *= (1.f / NR); S.w *= (1.f / NR);
    float n2 = S.x * S.x + S.y * S.y + S.z * S.z + S.w * S.w;
    n2 += __shfl_xor(n2, 1); n2 += __shfl_xor(n2, 2); n2 += __shfl_xor(n2, 4);
    const float scale = n2 / ((1.f + n2) * sqrtf(n2));
    u_s[tid * 4 + 0] = S.x * scale; u_s[tid * 4 + 1] = S.y * scale;
    u_s[tid * 4 + 2] = S.z * scale; u_s[tid * 4 + 3] = S.w * scale;
  }
  __syncthreads();

  float4 u = *reinterpret_cast<const float4*>(&u_s[sl * 4]);
  float l1[9];

  for (int it = 1; it <= 2; ++it) {
    float m = -3.0e38f, Z = 0.f;
    float4 T = make_float4(0.f, 0.f, 0.f, 0.f);
#pragma unroll
    for (int j = 0; j < 9; ++j) {
      float d = p[j].x * u.x + p[j].y * u.y + p[j].z * u.z + p[j].w * u.w;
      d += __shfl_xor(d, 1); d += __shfl_xor(d, 2); d += __shfl_xor(d, 4);
      float l;
      if (it == 1) { l1[j] = d; l = d; }
      else         { l = l1[j] + d; }
      const float mn = fmaxf(m, l);
      const float a = __expf(m - mn);
      const float e = __expf(l - mn);
      Z   = Z * a + e;
      T.x = T.x * a + e * p[j].x; T.y = T.y * a + e * p[j].y;
      T.z = T.z * a + e * p[j].z; T.w = T.w * a + e * p[j].w;
      m = mn;
    }
#pragma unroll
    for (int off = 8; off <= 32; off <<= 1) {
      const float m2 = __shfl_xor(m, off);
      const float Z2 = __shfl_xor(Z, off);
      float4 T2;
      T2.x = __shfl_xor(T.x, off); T2.y = __shfl_xor(T.y, off);
      T2.z = __shfl_xor(T.z, off); T2.w = __shfl_xor(T.w, off);
      merge4(m, Z, T, m2, Z2, T2);
    }
    if (lane < 8) {
      red_s[wave][sl][0] = m;   red_s[wave][sl][1] = Z;
      red_s[wave][sl][2] = T.x; red_s[wave][sl][3] = T.y;
      red_s[wave][sl][4] = T.z; red_s[wave][sl][5] = T.w;
    }
    __syncthreads();
    if (tid < 8) {
      float mm = red_s[0][tid][0], ZZ = red_s[0][tid][1];
      float4 TT = make_float4(red_s[0][tid][2], red_s[0][tid][3],
                              red_s[0][tid][4], red_s[0][tid][5]);
#pragma unroll
      for (int ww = 1; ww < 16; ++ww) {
        const float4 T2 = make_float4(red_s[ww][tid][2], red_s[ww][tid][3],
                                      red_s[ww][tid][4], red_s[ww][tid][5]);
        merge4(mm, ZZ, TT, red_s[ww][tid][0], red_s[ww][tid][1], T2);
      }
      const float inv = 1.f / ZZ;
      float4 S = make_float4(TT.x * inv, TT.y * inv, TT.z * inv, TT.w * inv);
      float n2 = S.x * S.x + S.y * S.y + S.z * S.z + S.w * S.w;
      n2 += __shfl_xor(n2, 1); n2 += __shfl_xor(n2, 2); n2 += __shfl_xor(n2, 4);
      const float scale = n2 / ((1.f + n2) * sqrtf(n2));
      if (it == 1) {
        u_s[tid * 4 + 0] = S.x * scale; u_s[tid * 4 + 1] = S.y * scale;
        u_s[tid * 4 + 2] = S.z * scale; u_s[tid * 4 + 3] = S.w * scale;
      } else {
        *reinterpret_cast<float4*>(out + ((size_t)b * NC + c) * NO + tid * 4) =
            make_float4(S.x * scale, S.y * scale, S.z * scale, S.w * scale);
      }
    }
    __syncthreads();
    if (it == 1) u = *reinterpret_cast<const float4*>(&u_s[sl * 4]);
  }
}

extern "C" void kernel_launch(void* const* d_in, const int* in_sizes, int n_in,
                              void* d_out, int out_size, void* d_ws, size_t ws_size,
                              hipStream_t stream) {
  const float* x = (const float*)d_in[0];
  // d_in[1] (cond) is unused by the reference computation
  const float* W = (const float*)d_in[2];
  float* out = (float*)d_out;

  float* xT = (float*)d_ws;                       // 18.9 MB
  const size_t xT_floats = (size_t)NR * NI * NB;
  float* P = xT + xT_floats;                      // 302 MB

  k_xpose<<<NR, 256, 0, stream>>>(x, xT);
  k_priors<<<dim3(NC, NR / 4), 256, 0, stream>>>(xT, W, P);
  k_route<<<dim3(NB, NC), 1024, 0, stream>>>(P, out);
}

// Round 15
// 254.238 us; speedup vs baseline: 1.7837x; 1.2544x over previous
//
#include <hip/hip_runtime.h>
#include <stdint.h>

#define NB 64
#define NR 1152
#define NI 64
#define NC 32
#define NO 32

typedef __attribute__((ext_vector_type(8))) short bf16x8;
typedef __attribute__((ext_vector_type(4))) float f32x4;

__device__ __forceinline__ uint16_t f2bf(float f) {
  uint32_t u = __float_as_uint(f);
  return (uint16_t)((u + 0x7FFFu + ((u >> 16) & 1u)) >> 16);
}
__device__ __forceinline__ float bf2f(uint16_t h) {
  return __uint_as_float(((uint32_t)h) << 16);
}

// ---------------------------------------------------------------------------
// T0: x[b,r,i] fp32 -> xbf_hi/xbf_lo [r][b][i] bf16 (9.44 MB each, ~8 us).
// hi = RNE-bf16(x); lo = RNE-bf16(x - hi)  (residual exact in fp32).
// ---------------------------------------------------------------------------
__global__ __launch_bounds__(256, 4)
void k_xcvt(const float* __restrict__ x, uint16_t* __restrict__ xh,
            uint16_t* __restrict__ xl) {
  const int r = blockIdx.x;
  const int t = threadIdx.x;
  const int b = t >> 2, i0 = (t & 3) * 16;
  const float4* src = reinterpret_cast<const float4*>(x + ((size_t)b * NR + r) * NI + i0);

  union { uint16_t us[16]; uint4 v[2]; } hb, lb;
#pragma unroll
  for (int k = 0; k < 4; ++k) {
    const float4 v = src[k];
    const float fv[4] = {v.x, v.y, v.z, v.w};
#pragma unroll
    for (int j = 0; j < 4; ++j) {
      const uint16_t h = f2bf(fv[j]);
      hb.us[k * 4 + j] = h;
      lb.us[k * 4 + j] = f2bf(fv[j] - bf2f(h));
    }
  }
  const size_t dst = ((size_t)r * NB + b) * NI + i0;
  *reinterpret_cast<uint4*>(xh + dst)     = hb.v[0];
  *reinterpret_cast<uint4*>(xh + dst + 8) = hb.v[1];
  *reinterpret_cast<uint4*>(xl + dst)     = lb.v[0];
  *reinterpret_cast<uint4*>(xl + dst + 8) = lb.v[1];
}

// ---------------------------------------------------------------------------
// K1 (MFMA): P[c,b,r,o] = sum_i x[b,r,i] * W[c,r,i,o] via split-bf16:
// x_hi*W_hi + x_lo*W_hi + x_hi*W_lo  (virtual K=192, 6 k-steps of 32).
// grid (NC, NR) c-fastest; block 256 = 4 waves; wave = m-tile (16 b).
// LDS: xhs/xls [b][i] bf16 swz, whs/wls [o][i] bf16 swz (24 KB total).
// Swizzle: byte ^= ((row&7)<<4) on 16B-aligned addrs (T2; residual 2-way=free).
// A/B frags filled with the SAME (lane,e)->k map (contiguous 8 i per lane)
// -> correct for any HW k-permutation. D layout (HW-verified m89):
// col = lane&15 (=o), row = (lane>>4)*4+reg (=b within tile).
// ---------------------------------------------------------------------------
__global__ __launch_bounds__(256, 6)
void k_priors(const uint16_t* __restrict__ xh, const uint16_t* __restrict__ xl,
              const float* __restrict__ W, float* __restrict__ P) {
  __shared__ __align__(16) uint16_t xhs[NB * NI];  // 8 KB
  __shared__ __align__(16) uint16_t xls[NB * NI];  // 8 KB
  __shared__ __align__(16) uint16_t whs[NO * NI];  // 4 KB
  __shared__ __align__(16) uint16_t wls[NO * NI];  // 4 KB

  const int tid  = threadIdx.x;
  const int lane = tid & 63;
  const int mt   = tid >> 6;     // wave = b-tile
  const int c    = blockIdx.x;
  const int r    = blockIdx.y;

  // ---- stage x hi/lo: thread: b = tid>>2, i0 = (tid&3)*16 (32B each) ----
  {
    const int b = tid >> 2, i0 = (tid & 3) * 16;
    const size_t src = ((size_t)r * NB + b) * NI + i0;
    const int sw = (b & 7) << 4;
    const int a0 = (b * 128 + i0 * 2) ^ sw;
    const int a1 = (b * 128 + (i0 + 8) * 2) ^ sw;
    uint4 v;
    v = *reinterpret_cast<const uint4*>(xh + src);
    *reinterpret_cast<uint4*>((char*)xhs + a0) = v;
    v = *reinterpret_cast<const uint4*>(xh + src + 8);
    *reinterpret_cast<uint4*>((char*)xhs + a1) = v;
    v = *reinterpret_cast<const uint4*>(xl + src);
    *reinterpret_cast<uint4*>((char*)xls + a0) = v;
    v = *reinterpret_cast<const uint4*>(xl + src + 8);
    *reinterpret_cast<uint4*>((char*)xls + a1) = v;
  }
  // ---- stage W: thread: i = tid>>2, o0 = (tid&3)*8; convert + transpose ----
  {
    const int i = tid >> 2, o0 = (tid & 3) * 8;
    const float* wsrc = W + (((size_t)c * NR + r) * NI + i) * NO + o0;
    const float4 f0 = *reinterpret_cast<const float4*>(wsrc);
    const float4 f1 = *reinterpret_cast<const float4*>(wsrc + 4);
    const float fv[8] = {f0.x, f0.y, f0.z, f0.w, f1.x, f1.y, f1.z, f1.w};
#pragma unroll
    for (int j = 0; j < 8; ++j) {
      const int o = o0 + j;
      const uint16_t h = f2bf(fv[j]);
      const uint16_t lo = f2bf(fv[j] - bf2f(h));
      const int ad = (o * 128 + i * 2) ^ ((o & 7) << 4);
      *reinterpret_cast<uint16_t*>((char*)whs + ad) = h;
      *reinterpret_cast<uint16_t*>((char*)wls + ad) = lo;
    }
  }
  __syncthreads();

  // ---- compute: 12 MFMA per wave ----
  const int lm = lane & 15;
  const int lg = lane >> 4;
  const int brow = mt * 16 + lm;
  const int aswz = (brow & 7) << 4;
  const int a0 = (brow * 128 + (8 * lg) * 2) ^ aswz;        // kseg 0
  const int a1 = (brow * 128 + (32 + 8 * lg) * 2) ^ aswz;   // kseg 1
  const int or0 = lm, or1 = 16 + lm;
  const int b00 = (or0 * 128 + (8 * lg) * 2) ^ ((or0 & 7) << 4);
  const int b01 = (or0 * 128 + (32 + 8 * lg) * 2) ^ ((or0 & 7) << 4);
  const int b10 = (or1 * 128 + (8 * lg) * 2) ^ ((or1 & 7) << 4);
  const int b11 = (or1 * 128 + (32 + 8 * lg) * 2) ^ ((or1 & 7) << 4);

#define RD(arr, off) (*reinterpret_cast<const bf16x8*>((const char*)(arr) + (off)))
#define MFMA(A, B, C) __builtin_amdgcn_mfma_f32_16x16x32_bf16(A, B, C, 0, 0, 0)

  f32x4 acc0 = {0.f, 0.f, 0.f, 0.f}, acc1 = acc0;
  {
    bf16x8 a, b;
    a = RD(xhs, a0);                                  // x_hi, kseg0
    b = RD(whs, b00); acc0 = MFMA(a, b, acc0);
    b = RD(whs, b10); acc1 = MFMA(a, b, acc1);
    b = RD(wls, b00); acc0 = MFMA(a, b, acc0);        // x_hi * W_lo
    b = RD(wls, b10); acc1 = MFMA(a, b, acc1);
    a = RD(xhs, a1);                                  // x_hi, kseg1
    b = RD(whs, b01); acc0 = MFMA(a, b, acc0);
    b = RD(whs, b11); acc1 = MFMA(a, b, acc1);
    b = RD(wls, b01); acc0 = MFMA(a, b, acc0);
    b = RD(wls, b11); acc1 = MFMA(a, b, acc1);
    a = RD(xls, a0);                                  // x_lo * W_hi, kseg0
    b = RD(whs, b00); acc0 = MFMA(a, b, acc0);
    b = RD(whs, b10); acc1 = MFMA(a, b, acc1);
    a = RD(xls, a1);                                  // x_lo * W_hi, kseg1
    b = RD(whs, b01); acc0 = MFMA(a, b, acc0);
    b = RD(whs, b11); acc1 = MFMA(a, b, acc1);
  }
#undef RD
#undef MFMA

  // ---- store: D col = lm (o), row = lg*4+reg (b within tile) ----
#pragma unroll
  for (int reg = 0; reg < 4; ++reg) {
    const int b = mt * 16 + lg * 4 + reg;
    float* dst = P + (((size_t)c * NB + b) * NR + r) * NO;
    dst[lm]      = acc0[reg];
    dst[16 + lm] = acc1[reg];
  }
}

// ---------------------------------------------------------------------------
// K2: full 3-iteration routing for one (c,b). block 1024 (16 waves).
// (unchanged, proven)
// ---------------------------------------------------------------------------
__device__ __forceinline__ void merge4(float& m, float& Z, float4& T,
                                       float m2, float Z2, const float4& T2) {
  const float mn = fmaxf(m, m2);
  const float a1 = __expf(m - mn), a2 = __expf(m2 - mn);
  Z   = Z * a1 + Z2 * a2;
  T.x = T.x * a1 + T2.x * a2;
  T.y = T.y * a1 + T2.y * a2;
  T.z = T.z * a1 + T2.z * a2;
  T.w = T.w * a1 + T2.w * a2;
  m = mn;
}

__global__ __launch_bounds__(1024, 1)
void k_route(const float* __restrict__ P, float* __restrict__ out) {
  __shared__ float red_s[16][8][8];
  __shared__ float u_s[NO];

  const int tid  = threadIdx.x;
  const int lane = tid & 63;
  const int wave = tid >> 6;
  const int sl   = tid & 7;
  const int grp  = tid >> 3;
  const int b    = blockIdx.x;
  const int c    = blockIdx.y;
  const float* Pb = P + ((size_t)c * NB + b) * ((size_t)NR * NO);

  float4 p[9];
#pragma unroll
  for (int j = 0; j < 9; ++j)
    p[j] = *reinterpret_cast<const float4*>(Pb + (size_t)(grp + 128 * j) * NO + sl * 4);

  {
    float4 T = p[0];
#pragma unroll
    for (int j = 1; j < 9; ++j) {
      T.x += p[j].x; T.y += p[j].y; T.z += p[j].z; T.w += p[j].w;
    }
#pragma unroll
    for (int off = 8; off <= 32; off <<= 1) {
      T.x += __shfl_xor(T.x, off); T.y += __shfl_xor(T.y, off);
      T.z += __shfl_xor(T.z, off); T.w += __shfl_xor(T.w, off);
    }
    if (lane < 8) {
      red_s[wave][sl][2] = T.x; red_s[wave][sl][3] = T.y;
      red_s[wave][sl][4] = T.z; red_s[wave][sl][5] = T.w;
    }
  }
  __syncthreads();
  if (tid < 8) {
    float4 S = make_float4(0.f, 0.f, 0.f, 0.f);
#pragma unroll
    for (int ww = 0; ww < 16; ++ww) {
      S.x += red_s[ww][tid][2]; S.y += red_s[ww][tid][3];
      S.z += red_s[ww][tid][4]; S.w += red_s[ww][tid][5];
    }
    S.x *= (1.f / NR); S.y *= (1.f / NR); S.z *= (1.f / NR); S.w *= (1.f / NR);
    float n2 = S.x * S.x + S.y * S.y + S.z * S.z + S.w * S.w;
    n2 += __shfl_xor(n2, 1); n2 += __shfl_xor(n2, 2); n2 += __shfl_xor(n2, 4);
    const float scale = n2 / ((1.f + n2) * sqrtf(n2));
    u_s[tid * 4 + 0] = S.x * scale; u_s[tid * 4 + 1] = S.y * scale;
    u_s[tid * 4 + 2] = S.z * scale; u_s[tid * 4 + 3] = S.w * scale;
  }
  __syncthreads();

  float4 u = *reinterpret_cast<const float4*>(&u_s[sl * 4]);
  float l1[9];

  for (int it = 1; it <= 2; ++it) {
    float m = -3.0e38f, Z = 0.f;
    float4 T = make_float4(0.f, 0.f, 0.f, 0.f);
#pragma unroll
    for (int j = 0; j < 9; ++j) {
      float d = p[j].x * u.x + p[j].y * u.y + p[j].z * u.z + p[j].w * u.w;
      d += __shfl_xor(d, 1); d += __shfl_xor(d, 2); d += __shfl_xor(d, 4);
      float l;
      if (it == 1) { l1[j] = d; l = d; }
      else         { l = l1[j] + d; }
      const float mn = fmaxf(m, l);
      const float a = __expf(m - mn);
      const float e = __expf(l - mn);
      Z   = Z * a + e;
      T.x = T.x * a + e * p[j].x; T.y = T.y * a + e * p[j].y;
      T.z = T.z * a + e * p[j].z; T.w = T.w * a + e * p[j].w;
      m = mn;
    }
#pragma unroll
    for (int off = 8; off <= 32; off <<= 1) {
      const float m2 = __shfl_xor(m, off);
      const float Z2 = __shfl_xor(Z, off);
      float4 T2;
      T2.x = __shfl_xor(T.x, off); T2.y = __shfl_xor(T.y, off);
      T2.z = __shfl_xor(T.z, off); T2.w = __shfl_xor(T.w, off);
      merge4(m, Z, T, m2, Z2, T2);
    }
    if (lane < 8) {
      red_s[wave][sl][0] = m;   red_s[wave][sl][1] = Z;
      red_s[wave][sl][2] = T.x; red_s[wave][sl][3] = T.y;
      red_s[wave][sl][4] = T.z; red_s[wave][sl][5] = T.w;
    }
    __syncthreads();
    if (tid < 8) {
      float mm = red_s[0][tid][0], ZZ = red_s[0][tid][1];
      float4 TT = make_float4(red_s[0][tid][2], red_s[0][tid][3],
                              red_s[0][tid][4], red_s[0][tid][5]);
#pragma unroll
      for (int ww = 1; ww < 16; ++ww) {
        const float4 T2 = make_float4(red_s[ww][tid][2], red_s[ww][tid][3],
                                      red_s[ww][tid][4], red_s[ww][tid][5]);
        merge4(mm, ZZ, TT, red_s[ww][tid][0], red_s[ww][tid][1], T2);
      }
      const float inv = 1.f / ZZ;
      float4 S = make_float4(TT.x * inv, TT.y * inv, TT.z * inv, TT.w * inv);
      float n2 = S.x * S.x + S.y * S.y + S.z * S.z + S.w * S.w;
      n2 += __shfl_xor(n2, 1); n2 += __shfl_xor(n2, 2); n2 += __shfl_xor(n2, 4);
      const float scale = n2 / ((1.f + n2) * sqrtf(n2));
      if (it == 1) {
        u_s[tid * 4 + 0] = S.x * scale; u_s[tid * 4 + 1] = S.y * scale;
        u_s[tid * 4 + 2] = S.z * scale; u_s[tid * 4 + 3] = S.w * scale;
      } else {
        *reinterpret_cast<float4*>(out + ((size_t)b * NC + c) * NO + tid * 4) =
            make_float4(S.x * scale, S.y * scale, S.z * scale, S.w * scale);
      }
    }
    __syncthreads();
    if (it == 1) u = *reinterpret_cast<const float4*>(&u_s[sl * 4]);
  }
}

extern "C" void kernel_launch(void* const* d_in, const int* in_sizes, int n_in,
                              void* d_out, int out_size, void* d_ws, size_t ws_size,
                              hipStream_t stream) {
  const float* x = (const float*)d_in[0];
  // d_in[1] (cond) is unused by the reference computation
  const float* W = (const float*)d_in[2];
  float* out = (float*)d_out;

  uint16_t* xh = (uint16_t*)d_ws;                     // 9.44 MB
  const size_t xbf_elems = (size_t)NR * NB * NI;
  uint16_t* xl = xh + xbf_elems;                      // 9.44 MB
  float* P = (float*)(xl + xbf_elems);                // 302 MB

  k_xcvt<<<NR, 256, 0, stream>>>(x, xh, xl);
  k_priors<<<dim3(NC, NR), 256, 0, stream>>>(xh, xl, W, P);
  k_route<<<dim3(NB, NC), 1024, 0, stream>>>(P, out);
}

// Round 16
// 253.235 us; speedup vs baseline: 1.7908x; 1.0040x over previous
//
#include <hip/hip_runtime.h>
#include <stdint.h>

#define NB 64
#define NR 1152
#define NI 64
#define NC 32
#define NO 32

typedef __attribute__((ext_vector_type(8))) short bf16x8;
typedef __attribute__((ext_vector_type(4))) float f32x4;
typedef float float4v __attribute__((ext_vector_type(4)));

__device__ __forceinline__ uint16_t f2bf(float f) {
  uint32_t u = __float_as_uint(f);
  return (uint16_t)((u + 0x7FFFu + ((u >> 16) & 1u)) >> 16);
}
__device__ __forceinline__ float bf2f(uint16_t h) {
  return __uint_as_float(((uint32_t)h) << 16);
}

// ---------------------------------------------------------------------------
// T0: x[b,r,i] fp32 -> xbf_hi/xbf_lo [r][b][i] bf16 (9.44 MB each, ~8 us).
// hi = RNE-bf16(x); lo = RNE-bf16(x - hi). x read NT (never re-read).
// ---------------------------------------------------------------------------
__global__ __launch_bounds__(256, 4)
void k_xcvt(const float* __restrict__ x, uint16_t* __restrict__ xh,
            uint16_t* __restrict__ xl) {
  const int r = blockIdx.x;
  const int t = threadIdx.x;
  const int b = t >> 2, i0 = (t & 3) * 16;
  const float* src = x + ((size_t)b * NR + r) * NI + i0;

  union { uint16_t us[16]; uint4 v[2]; } hb, lb;
#pragma unroll
  for (int k = 0; k < 4; ++k) {
    const float4v v = __builtin_nontemporal_load(
        reinterpret_cast<const float4v*>(src + 4 * k));
#pragma unroll
    for (int j = 0; j < 4; ++j) {
      const uint16_t h = f2bf(v[j]);
      hb.us[k * 4 + j] = h;
      lb.us[k * 4 + j] = f2bf(v[j] - bf2f(h));
    }
  }
  const size_t dst = ((size_t)r * NB + b) * NI + i0;
  *reinterpret_cast<uint4*>(xh + dst)     = hb.v[0];
  *reinterpret_cast<uint4*>(xh + dst + 8) = hb.v[1];
  *reinterpret_cast<uint4*>(xl + dst)     = lb.v[0];
  *reinterpret_cast<uint4*>(xl + dst + 8) = lb.v[1];
}

// ---------------------------------------------------------------------------
// K1 (MFMA): P[c,b,r,o] = sum_i x[b,r,i] * W[c,r,i,o] via split-bf16
// (round-15 proven: 3 terms, virtual K=192). Deltas this round:
//  - W loads NT (read-once; keep xh/xl L3-resident)
//  - P stores NT (consumed next kernel, >L3 anyway; stop L3 thrash)
//  - W-stage LDS writes packed u32 i-pairs (same layout, half the LDS ops)
// ---------------------------------------------------------------------------
__global__ __launch_bounds__(256, 6)
void k_priors(const uint16_t* __restrict__ xh, const uint16_t* __restrict__ xl,
              const float* __restrict__ W, float* __restrict__ P) {
  __shared__ __align__(16) uint16_t xhs[NB * NI];  // 8 KB
  __shared__ __align__(16) uint16_t xls[NB * NI];  // 8 KB
  __shared__ __align__(16) uint16_t whs[NO * NI];  // 4 KB
  __shared__ __align__(16) uint16_t wls[NO * NI];  // 4 KB

  const int tid  = threadIdx.x;
  const int lane = tid & 63;
  const int mt   = tid >> 6;     // wave = b-tile
  const int c    = blockIdx.x;
  const int r    = blockIdx.y;

  // ---- stage x hi/lo: thread: b = tid>>2, i0 = (tid&3)*16 (32B each) ----
  {
    const int b = tid >> 2, i0 = (tid & 3) * 16;
    const size_t src = ((size_t)r * NB + b) * NI + i0;
    const int sw = (b & 7) << 4;
    const int a0 = (b * 128 + i0 * 2) ^ sw;
    const int a1 = (b * 128 + (i0 + 8) * 2) ^ sw;
    uint4 v;
    v = *reinterpret_cast<const uint4*>(xh + src);
    *reinterpret_cast<uint4*>((char*)xhs + a0) = v;
    v = *reinterpret_cast<const uint4*>(xh + src + 8);
    *reinterpret_cast<uint4*>((char*)xhs + a1) = v;
    v = *reinterpret_cast<const uint4*>(xl + src);
    *reinterpret_cast<uint4*>((char*)xls + a0) = v;
    v = *reinterpret_cast<const uint4*>(xl + src + 8);
    *reinterpret_cast<uint4*>((char*)xls + a1) = v;
  }
  // ---- stage W: thread: i-pair i2 = tid>>3 (i = 2i2, 2i2+1), o0 = (tid&7)*4.
  //      NT fp32 loads, convert hi/lo, pack i-pair into u32, store [o][i] swz.
  //      Byte layout identical to round 15 (i-pairs adjacent in [o][i*2B]). ----
  {
    const int i2 = tid >> 3, o0 = (tid & 7) * 4;
    const float* wsrc = W + (((size_t)c * NR + r) * NI + 2 * i2) * NO + o0;
    const float4v f0 = __builtin_nontemporal_load(
        reinterpret_cast<const float4v*>(wsrc));        // i = 2i2
    const float4v f1 = __builtin_nontemporal_load(
        reinterpret_cast<const float4v*>(wsrc + NO));   // i = 2i2+1
#pragma unroll
    for (int j = 0; j < 4; ++j) {
      const int o = o0 + j;
      const float fa = f0[j], fb = f1[j];
      const uint16_t ha = f2bf(fa), hb = f2bf(fb);
      const uint16_t la = f2bf(fa - bf2f(ha)), lb = f2bf(fb - bf2f(hb));
      const int ad = (o * 128 + i2 * 4) ^ ((o & 7) << 4);
      *reinterpret_cast<uint32_t*>((char*)whs + ad) = (uint32_t)ha | ((uint32_t)hb << 16);
      *reinterpret_cast<uint32_t*>((char*)wls + ad) = (uint32_t)la | ((uint32_t)lb << 16);
    }
  }
  __syncthreads();

  // ---- compute: 12 MFMA per wave (unchanged, proven) ----
  const int lm = lane & 15;
  const int lg = lane >> 4;
  const int brow = mt * 16 + lm;
  const int aswz = (brow & 7) << 4;
  const int a0 = (brow * 128 + (8 * lg) * 2) ^ aswz;        // kseg 0
  const int a1 = (brow * 128 + (32 + 8 * lg) * 2) ^ aswz;   // kseg 1
  const int or0 = lm, or1 = 16 + lm;
  const int b00 = (or0 * 128 + (8 * lg) * 2) ^ ((or0 & 7) << 4);
  const int b01 = (or0 * 128 + (32 + 8 * lg) * 2) ^ ((or0 & 7) << 4);
  const int b10 = (or1 * 128 + (8 * lg) * 2) ^ ((or1 & 7) << 4);
  const int b11 = (or1 * 128 + (32 + 8 * lg) * 2) ^ ((or1 & 7) << 4);

#define RD(arr, off) (*reinterpret_cast<const bf16x8*>((const char*)(arr) + (off)))
#define MFMA(A, B, C) __builtin_amdgcn_mfma_f32_16x16x32_bf16(A, B, C, 0, 0, 0)

  f32x4 acc0 = {0.f, 0.f, 0.f, 0.f}, acc1 = acc0;
  {
    bf16x8 a, b;
    a = RD(xhs, a0);                                  // x_hi, kseg0
    b = RD(whs, b00); acc0 = MFMA(a, b, acc0);
    b = RD(whs, b10); acc1 = MFMA(a, b, acc1);
    b = RD(wls, b00); acc0 = MFMA(a, b, acc0);        // x_hi * W_lo
    b = RD(wls, b10); acc1 = MFMA(a, b, acc1);
    a = RD(xhs, a1);                                  // x_hi, kseg1
    b = RD(whs, b01); acc0 = MFMA(a, b, acc0);
    b = RD(whs, b11); acc1 = MFMA(a, b, acc1);
    b = RD(wls, b01); acc0 = MFMA(a, b, acc0);
    b = RD(wls, b11); acc1 = MFMA(a, b, acc1);
    a = RD(xls, a0);                                  // x_lo * W_hi, kseg0
    b = RD(whs, b00); acc0 = MFMA(a, b, acc0);
    b = RD(whs, b10); acc1 = MFMA(a, b, acc1);
    a = RD(xls, a1);                                  // x_lo * W_hi, kseg1
    b = RD(whs, b01); acc0 = MFMA(a, b, acc0);
    b = RD(whs, b11); acc1 = MFMA(a, b, acc1);
  }
#undef RD
#undef MFMA

  // ---- store (NT): D col = lm (o), row = lg*4+reg (b within tile) ----
#pragma unroll
  for (int reg = 0; reg < 4; ++reg) {
    const int b = mt * 16 + lg * 4 + reg;
    float* dst = P + (((size_t)c * NB + b) * NR + r) * NO;
    __builtin_nontemporal_store(acc0[reg], dst + lm);
    __builtin_nontemporal_store(acc1[reg], dst + 16 + lm);
  }
}

// ---------------------------------------------------------------------------
// K2: full 3-iteration routing for one (c,b). block 1024 (16 waves).
// Unchanged except P loads are NT (read-once stream).
// ---------------------------------------------------------------------------
__device__ __forceinline__ void merge4(float& m, float& Z, float4& T,
                                       float m2, float Z2, const float4& T2) {
  const float mn = fmaxf(m, m2);
  const float a1 = __expf(m - mn), a2 = __expf(m2 - mn);
  Z   = Z * a1 + Z2 * a2;
  T.x = T.x * a1 + T2.x * a2;
  T.y = T.y * a1 + T2.y * a2;
  T.z = T.z * a1 + T2.z * a2;
  T.w = T.w * a1 + T2.w * a2;
  m = mn;
}

__global__ __launch_bounds__(1024, 1)
void k_route(const float* __restrict__ P, float* __restrict__ out) {
  __shared__ float red_s[16][8][8];
  __shared__ float u_s[NO];

  const int tid  = threadIdx.x;
  const int lane = tid & 63;
  const int wave = tid >> 6;
  const int sl   = tid & 7;
  const int grp  = tid >> 3;
  const int b    = blockIdx.x;
  const int c    = blockIdx.y;
  const float* Pb = P + ((size_t)c * NB + b) * ((size_t)NR * NO);

  float4 p[9];
#pragma unroll
  for (int j = 0; j < 9; ++j) {
    const float4v t = __builtin_nontemporal_load(
        reinterpret_cast<const float4v*>(Pb + (size_t)(grp + 128 * j) * NO + sl * 4));
    p[j].x = t.x; p[j].y = t.y; p[j].z = t.z; p[j].w = t.w;
  }

  {
    float4 T = p[0];
#pragma unroll
    for (int j = 1; j < 9; ++j) {
      T.x += p[j].x; T.y += p[j].y; T.z += p[j].z; T.w += p[j].w;
    }
#pragma unroll
    for (int off = 8; off <= 32; off <<= 1) {
      T.x += __shfl_xor(T.x, off); T.y += __shfl_xor(T.y, off);
      T.z += __shfl_xor(T.z, off); T.w += __shfl_xor(T.w, off);
    }
    if (lane < 8) {
      red_s[wave][sl][2] = T.x; red_s[wave][sl][3] = T.y;
      red_s[wave][sl][4] = T.z; red_s[wave][sl][5] = T.w;
    }
  }
  __syncthreads();
  if (tid < 8) {
    float4 S = make_float4(0.f, 0.f, 0.f, 0.f);
#pragma unroll
    for (int ww = 0; ww < 16; ++ww) {
      S.x += red_s[ww][tid][2]; S.y += red_s[ww][tid][3];
      S.z += red_s[ww][tid][4]; S.w += red_s[ww][tid][5];
    }
    S.x *= (1.f / NR); S.y *= (1.f / NR); S.z *= (1.f / NR); S.w *= (1.f / NR);
    float n2 = S.x * S.x + S.y * S.y + S.z * S.z + S.w * S.w;
    n2 += __shfl_xor(n2, 1); n2 += __shfl_xor(n2, 2); n2 += __shfl_xor(n2, 4);
    const float scale = n2 / ((1.f + n2) * sqrtf(n2));
    u_s[tid * 4 + 0] = S.x * scale; u_s[tid * 4 + 1] = S.y * scale;
    u_s[tid * 4 + 2] = S.z * scale; u_s[tid * 4 + 3] = S.w * scale;
  }
  __syncthreads();

  float4 u = *reinterpret_cast<const float4*>(&u_s[sl * 4]);
  float l1[9];

  for (int it = 1; it <= 2; ++it) {
    float m = -3.0e38f, Z = 0.f;
    float4 T = make_float4(0.f, 0.f, 0.f, 0.f);
#pragma unroll
    for (int j = 0; j < 9; ++j) {
      float d = p[j].x * u.x + p[j].y * u.y + p[j].z * u.z + p[j].w * u.w;
      d += __shfl_xor(d, 1); d += __shfl_xor(d, 2); d += __shfl_xor(d, 4);
      float l;
      if (it == 1) { l1[j] = d; l = d; }
      else         { l = l1[j] + d; }
      const float mn = fmaxf(m, l);
      const float a = __expf(m - mn);
      const float e = __expf(l - mn);
      Z   = Z * a + e;
      T.x = T.x * a + e * p[j].x; T.y = T.y * a + e * p[j].y;
      T.z = T.z * a + e * p[j].z; T.w = T.w * a + e * p[j].w;
      m = mn;
    }
#pragma unroll
    for (int off = 8; off <= 32; off <<= 1) {
      const float m2 = __shfl_xor(m, off);
      const float Z2 = __shfl_xor(Z, off);
      float4 T2;
      T2.x = __shfl_xor(T.x, off); T2.y = __shfl_xor(T.y, off);
      T2.z = __shfl_xor(T.z, off); T2.w = __shfl_xor(T.w, off);
      merge4(m, Z, T, m2, Z2, T2);
    }
    if (lane < 8) {
      red_s[wave][sl][0] = m;   red_s[wave][sl][1] = Z;
      red_s[wave][sl][2] = T.x; red_s[wave][sl][3] = T.y;
      red_s[wave][sl][4] = T.z; red_s[wave][sl][5] = T.w;
    }
    __syncthreads();
    if (tid < 8) {
      float mm = red_s[0][tid][0], ZZ = red_s[0][tid][1];
      float4 TT = make_float4(red_s[0][tid][2], red_s[0][tid][3],
                              red_s[0][tid][4], red_s[0][tid][5]);
#pragma unroll
      for (int ww = 1; ww < 16; ++ww) {
        const float4 T2 = make_float4(red_s[ww][tid][2], red_s[ww][tid][3],
                                      red_s[ww][tid][4], red_s[ww][tid][5]);
        merge4(mm, ZZ, TT, red_s[ww][tid][0], red_s[ww][tid][1], T2);
      }
      const float inv = 1.f / ZZ;
      float4 S = make_float4(TT.x * inv, TT.y * inv, TT.z * inv, TT.w * inv);
      float n2 = S.x * S.x + S.y * S.y + S.z * S.z + S.w * S.w;
      n2 += __shfl_xor(n2, 1); n2 += __shfl_xor(n2, 2); n2 += __shfl_xor(n2, 4);
      const float scale = n2 / ((1.f + n2) * sqrtf(n2));
      if (it == 1) {
        u_s[tid * 4 + 0] = S.x * scale; u_s[tid * 4 + 1] = S.y * scale;
        u_s[tid * 4 + 2] = S.z * scale; u_s[tid * 4 + 3] = S.w * scale;
      } else {
        *reinterpret_cast<float4*>(out + ((size_t)b * NC + c) * NO + tid * 4) =
            make_float4(S.x * scale, S.y * scale, S.z * scale, S.w * scale);
      }
    }
    __syncthreads();
    if (it == 1) u = *reinterpret_cast<const float4*>(&u_s[sl * 4]);
  }
}

extern "C" void kernel_launch(void* const* d_in, const int* in_sizes, int n_in,
                              void* d_out, int out_size, void* d_ws, size_t ws_size,
                              hipStream_t stream) {
  const float* x = (const float*)d_in[0];
  // d_in[1] (cond) is unused by the reference computation
  const float* W = (const float*)d_in[2];
  float* out = (float*)d_out;

  uint16_t* xh = (uint16_t*)d_ws;                     // 9.44 MB
  const size_t xbf_elems = (size_t)NR * NB * NI;
  uint16_t* xl = xh + xbf_elems;                      // 9.44 MB
  float* P = (float*)(xl + xbf_elems);                // 302 MB

  k_xcvt<<<NR, 256, 0, stream>>>(x, xh, xl);
  k_priors<<<dim3(NC, NR), 256, 0, stream>>>(xh, xl, W, P);
  k_route<<<dim3(NB, NC), 1024, 0, stream>>>(P, out);
}